// Round 8
// baseline (374.206 us; speedup 1.0000x reference)
//
#include <hip/hip_runtime.h>
#include <math.h>

#define BATCH 32768
#define SEQLEN 200
#define PSTEPS 50
#define HID 32
#define LDS_PAD 36   // float row stride 36 -> mild bank aliasing only (m136)

typedef __attribute__((ext_vector_type(2))) _Float16 half2v;
typedef __attribute__((ext_vector_type(8))) _Float16 half8v;
typedef __attribute__((ext_vector_type(2))) __fp16   fp16x2;   // cvt_pkrtz return type
typedef __attribute__((ext_vector_type(4))) float floatx4;
typedef __attribute__((ext_vector_type(2))) float float2v;

#define EXP2 __builtin_amdgcn_exp2f      // v_exp_f32: 2^x
#define RCPF __builtin_amdgcn_rcpf       // v_rcp_f32
#define PKRTZ __builtin_amdgcn_cvt_pkrtz // v_cvt_pkrtz_f16_f32
#define MED3 __builtin_amdgcn_fmed3f     // v_med3_f32
#define FMA2 __builtin_elementwise_fma   // <2 x float> fma -> v_pk_fma_f32

#define L1C 1.4426950408889634f          // log2(e)
#define L2C 2.8853900817779268f          // 2*log2(e)

union H8 { unsigned int u[4]; half8v h; half2v h2[4]; };
union HU { fp16x2 h; unsigned int u; };

__device__ __forceinline__ unsigned int pk(float a, float b) {
    HU t; t.h = PKRTZ(a, b); return t.u;
}

// R18 = R17 + x-MFMA hoist. The per-step critical path is
//   ds_write h -> ds_read h (~120cyc) -> pk -> mfma(a2) -> mfma(ah) -> gates.
// But mfma(a2,B2[n],0) depends ONLY on xv (prefetched a full step earlier),
// not on the recurrence. Hoisting all 8 x-MFMAs to the TOP of the iteration
// (before the h read) lets them execute inside the h-latency window and cuts
// one MFMA latency per tile off the serial chain. Dataflow and accumulation
// order unchanged (mfma(ah,Bh,acc_x) exactly as before): bit-identical.
// Costs ~32 extra live VGPRs — harmless at the grid-capped 2 waves/SIMD.
// Decode untouched (its x operand pd is the late one there).
// Everything else per R17/R14: one wave = private 16-batch group, private
// LDS h-region, no barriers, no lgkmcnt drain, float2-packed gate math,
// unroll 2, evens-first h-MFMAs, anti-phase s_sleep stagger.
// C layout: row(batch)=quad*4+reg, col(gate)=lane&15; A: m=lane&15, k=quad*8+j.
__global__ __launch_bounds__(256, 2)
void lstm_mfma_kernel(const float* __restrict__ hist, const float* __restrict__ W_ih,
                      const float* __restrict__ W_hh, const float* __restrict__ b_ih,
                      const float* __restrict__ b_hh, const float* __restrict__ W_pred,
                      const float* __restrict__ b_pred, float* __restrict__ out)
{
    const int lane = threadIdx.x & 63;
    const int wv   = threadIdx.x >> 6;
    const int m    = lane & 15;
    const int quad = lane >> 4;
    const int elem0 = (blockIdx.x * 4 + wv) * 16;

    // anti-phase: co-resident pair assumed (k, k+256) for 512-block grid
    if ((blockIdx.x >> 8) & 1) __builtin_amdgcn_s_sleep(12);

    __shared__ __align__(16) float h_lds_all[4][16][LDS_PAD];
    float (*hl)[LDS_PAD] = h_lds_all[wv];    // per-wave region: no __syncthreads ever

    // ---- resident weight fragments (f16, exp-scale folded; tiles 0,1=i 2,3=f 4,5=g 6,7=o) ----
    const float esc[4] = { -L1C, -L1C, L2C, -L1C };   // i,f,g,o exp2-domain scales
    half8v Bh[8], B2[8];
    #pragma unroll
    for (int n = 0; n < 8; ++n) {
        const int gc = n * 16 + m;           // gate row 0..127
        const float sc = esc[n >> 1];
        H8 bh;
        #pragma unroll
        for (int jj = 0; jj < 4; ++jj) {
            bh.h2[jj] = (half2v){ (_Float16)(sc * W_hh[gc * HID + quad * 8 + 2 * jj]),
                                  (_Float16)(sc * W_hh[gc * HID + quad * 8 + 2 * jj + 1]) };
        }
        Bh[n] = bh.h;
        H8 b2; b2.u[0] = b2.u[1] = b2.u[2] = b2.u[3] = 0u;
        if (quad == 0) {
            b2.h2[0] = (half2v){ (_Float16)(sc * W_ih[gc * 4 + 0]), (_Float16)(sc * W_ih[gc * 4 + 1]) };
            b2.h2[1] = (half2v){ (_Float16)(sc * W_ih[gc * 4 + 2]), (_Float16)(sc * W_ih[gc * 4 + 3]) };
            float bsum = sc * (b_ih[gc] + b_hh[gc]);
            _Float16 bhi = (_Float16)bsum;
            _Float16 blo = (_Float16)(bsum - (float)bhi);   // bias exact to ~2^-24
            b2.h2[2] = (half2v){ bhi, blo };                // K rows 4,5 (A = 1,1)
        }
        B2[n] = b2.h;
    }
    const unsigned int one2 = 0x3C003C00u;   // (1.0h, 1.0h)
    const floatx4 zf4 = { 0.f, 0.f, 0.f, 0.f };

    // ---- init h = 0 (LDS), c = 0 (regs) ----
    float cst[2][4];
    #pragma unroll
    for (int hf = 0; hf < 2; ++hf)
        #pragma unroll
        for (int r = 0; r < 4; ++r) { cst[hf][r] = 0.f; hl[quad * 4 + r][hf * 16 + m] = 0.f; }
    // no drain needed: DS pipe is in-order per wave

    // ---- encode: 200 steps, unrolled 2x for scheduling window ----
    const float4* xp = (const float4*)(hist + (size_t)(elem0 + m) * (SEQLEN * 4));
    float4 xv = xp[0];
    #pragma unroll 2
    for (int t = 0; t < SEQLEN; ++t) {
        // ---- x-MFMAs FIRST: depend only on xv (prefetched last iteration),
        //      execute inside the h ds_read latency window ----
        const unsigned int tx0 = pk(xv.x, xv.y), tx1 = pk(xv.z, xv.w);
        H8 a2u;
        a2u.u[0] = (quad == 0) ? tx0 : 0u;
        a2u.u[1] = (quad == 0) ? tx1 : 0u;
        a2u.u[2] = (quad == 0) ? one2 : 0u;
        a2u.u[3] = 0u;
        const half8v a2 = a2u.h;

        floatx4 accx[8];
        #pragma unroll
        for (int n = 0; n < 8; ++n)
            accx[n] = __builtin_amdgcn_mfma_f32_16x16x32_f16(a2, B2[n], zf4, 0, 0, 0);

        // ---- h fragment (the serial-chain load) ----
        float4 h0 = *(const float4*)&hl[m][quad * 8];
        float4 h1 = *(const float4*)&hl[m][quad * 8 + 4];
        H8 ahu;
        ahu.u[0] = pk(h0.x, h0.y); ahu.u[1] = pk(h0.z, h0.w);
        ahu.u[2] = pk(h1.x, h1.y); ahu.u[3] = pk(h1.z, h1.w);
        const half8v ah = ahu.h;

        const int tn = (t + 1 < SEQLEN) ? t + 1 : SEQLEN - 1;
        float4 xn = xp[tn];                  // prefetch stays in flight

        // evens first: hf=0's acc tiles (0,2,4,6) complete earliest
        floatx4 acc[8];
        #pragma unroll
        for (int nn = 0; nn < 8; ++nn) {
            const int n = (nn < 4) ? (nn * 2) : ((nn - 4) * 2 + 1);
            acc[n] = __builtin_amdgcn_mfma_f32_16x16x32_f16(ah, Bh[n], accx[n], 0, 0, 0);
        }
        // gates arrive in exp2 domain; cell pairs packed as float2 -> v_pk_* ops
        #pragma unroll
        for (int hf = 0; hf < 2; ++hf) {
            #pragma unroll
            for (int pr = 0; pr < 2; ++pr) {
                const int r0 = pr * 2, r1 = r0 + 1;
                const float2v ei = { EXP2(acc[0 + hf][r0]), EXP2(acc[0 + hf][r1]) };
                const float2v ef = { EXP2(acc[2 + hf][r0]), EXP2(acc[2 + hf][r1]) };
                const float2v eg = { EXP2(acc[4 + hf][r0]), EXP2(acc[4 + hf][r1]) };
                const float2v eo = { EXP2(acc[6 + hf][r0]), EXP2(acc[6 + hf][r1]) };
                // cn = c/(1+ef) + (eg-1)/((1+ei)(1+eg)) ; rcp shared across pair
                const float2v pf = 1.f + ef;
                const float2v t1 = (1.f + ei) * (1.f + eg);
                const float2v cc = { cst[hf][r0], cst[hf][r1] };
                const float2v num = FMA2(cc, t1, (eg - 1.f) * pf);
                const float2v d  = t1 * pf;                 // <= 2^52 each
                const float   R  = RCPF(d.x * d.y);         // <= 2^104: safe
                const float2v dsw = { d.y, d.x };
                const float2v cn  = num * (R * dsw);
                // tanh input clamp +-12: EXACT (tanh(12)==1.0f in fp32)
                const float2v cna = { MED3(cn.x, -12.f, 12.f), MED3(cn.y, -12.f, 12.f) };
                const float2v ea  = cna * L2C;
                const float2v ec  = { EXP2(ea.x), EXP2(ea.y) };
                const float2v dh  = (1.f + eo) * (1.f + ec);
                const float   Rh  = RCPF(dh.x * dh.y);
                const float2v dhsw = { dh.y, dh.x };
                const float2v hn  = (ec - 1.f) * (Rh * dhsw);

                cst[hf][r0] = cn.x; cst[hf][r1] = cn.y;     // state UNclamped (matches ref)
                hl[quad * 4 + r0][hf * 16 + m] = hn.x;
                hl[quad * 4 + r1][hf * 16 + m] = hn.y;
            }
        }
        // no lgkmcnt drain: DS in-order per wave; compiler can't hoist the
        // may-aliasing next-step reads above these writes
        xv = xn;
    }

    // ---- decode: 50 steps (c reset to 0 -> f-gate dead; tiles 2,3 skipped) ----
    float wp[4][8];
    #pragma unroll
    for (int d = 0; d < 4; ++d)
        #pragma unroll
        for (int j = 0; j < 8; ++j) wp[d][j] = W_pred[d * HID + quad * 8 + j];
    float bp[4] = { b_pred[0], b_pred[1], b_pred[2], b_pred[3] };

    float* op = out + (size_t)(elem0 + m) * (PSTEPS * 4);
    #pragma unroll 1
    for (int p = 0; p < PSTEPS; ++p) {
        float4 h0 = *(const float4*)&hl[m][quad * 8];
        float4 h1 = *(const float4*)&hl[m][quad * 8 + 4];
        const float hv[8] = { h0.x, h0.y, h0.z, h0.w, h1.x, h1.y, h1.z, h1.w };

        float pd[4];
        #pragma unroll
        for (int d = 0; d < 4; ++d) {
            float s = 0.f;
            #pragma unroll
            for (int j = 0; j < 8; ++j) s = fmaf(hv[j], wp[d][j], s);
            s += __shfl_xor(s, 16);
            s += __shfl_xor(s, 32);
            pd[d] = s + bp[d];
        }
        if (quad == 0) *(float4*)(op + p * 4) = make_float4(pd[0], pd[1], pd[2], pd[3]);

        if (p + 1 < PSTEPS) {
            H8 ahu;
            ahu.u[0] = pk(hv[0], hv[1]); ahu.u[1] = pk(hv[2], hv[3]);
            ahu.u[2] = pk(hv[4], hv[5]); ahu.u[3] = pk(hv[6], hv[7]);
            const half8v ah = ahu.h;
            const unsigned int tx0 = pk(pd[0], pd[1]), tx1 = pk(pd[2], pd[3]);
            H8 a2u;
            a2u.u[0] = (quad == 0) ? tx0 : 0u;
            a2u.u[1] = (quad == 0) ? tx1 : 0u;
            a2u.u[2] = (quad == 0) ? one2 : 0u;
            a2u.u[3] = 0u;
            const half8v a2 = a2u.h;

            floatx4 acc[6];   // tiles 0,1=i ; 4,5=g ; 6,7=o
            #pragma unroll
            for (int nn = 0; nn < 6; ++nn) {
                const int n = (nn < 2) ? nn : nn + 2;
                floatx4 a = __builtin_amdgcn_mfma_f32_16x16x32_f16(a2, B2[n], zf4, 0, 0, 0);
                acc[nn] = __builtin_amdgcn_mfma_f32_16x16x32_f16(ah, Bh[n], a, 0, 0, 0);
            }
            #pragma unroll
            for (int hf = 0; hf < 2; ++hf) {
                #pragma unroll
                for (int pr = 0; pr < 2; ++pr) {
                    const int r0 = pr * 2, r1 = r0 + 1;
                    const float2v ei = { EXP2(acc[0 + hf][r0]), EXP2(acc[0 + hf][r1]) };
                    const float2v eg = { EXP2(acc[2 + hf][r0]), EXP2(acc[2 + hf][r1]) };
                    const float2v eo = { EXP2(acc[4 + hf][r0]), EXP2(acc[4 + hf][r1]) };
                    // cn = (eg-1)/((1+ei)(1+eg)) (c==0); |cn|<1
                    const float2v d  = (1.f + ei) * (1.f + eg);
                    const float   R  = RCPF(d.x * d.y);
                    const float2v dsw = { d.y, d.x };
                    const float2v cn  = (eg - 1.f) * (R * dsw);
                    const float2v ea  = cn * L2C;
                    const float2v ec  = { EXP2(ea.x), EXP2(ea.y) };   // ec in [2^-2.9, 2^2.9]
                    const float2v dh  = (1.f + eo) * (1.f + ec);
                    const float   Rh  = RCPF(dh.x * dh.y);
                    const float2v dhsw = { dh.y, dh.x };
                    const float2v hn  = (ec - 1.f) * (Rh * dhsw);

                    hl[quad * 4 + r0][hf * 16 + m] = hn.x;
                    hl[quad * 4 + r1][hf * 16 + m] = hn.y;
                }
            }
            // no lgkmcnt drain (DS in-order per wave)
        }
    }
}

extern "C" void kernel_launch(void* const* d_in, const int* in_sizes, int n_in,
                              void* d_out, int out_size, void* d_ws, size_t ws_size,
                              hipStream_t stream) {
    const float* hist   = (const float*)d_in[0];
    const float* W_ih   = (const float*)d_in[1];
    const float* W_hh   = (const float*)d_in[2];
    const float* b_ih   = (const float*)d_in[3];
    const float* b_hh   = (const float*)d_in[4];
    const float* W_pred = (const float*)d_in[5];
    const float* b_pred = (const float*)d_in[6];
    float* out = (float*)d_out;

    const int blocks = (BATCH / 16) / 4;   // 512 blocks = 2048 waves, 2/SIMD
    lstm_mfma_kernel<<<blocks, 256, 0, stream>>>(hist, W_ih, W_hh, b_ih, b_hh,
                                                 W_pred, b_pred, out);
}

// Round 9
// 368.239 us; speedup vs baseline: 1.0162x; 1.0162x over previous
//
#include <hip/hip_runtime.h>
#include <math.h>

#define BATCH 32768
#define SEQLEN 200
#define PSTEPS 50
#define HID 32
#define LDS_PAD 36   // float row stride 36 -> mild bank aliasing only (m136)

typedef __attribute__((ext_vector_type(2))) _Float16 half2v;
typedef __attribute__((ext_vector_type(8))) _Float16 half8v;
typedef __attribute__((ext_vector_type(2))) __fp16   fp16x2;   // cvt_pkrtz return type
typedef __attribute__((ext_vector_type(4))) float floatx4;
typedef __attribute__((ext_vector_type(2))) float float2v;

#define EXP2 __builtin_amdgcn_exp2f      // v_exp_f32: 2^x
#define RCPF __builtin_amdgcn_rcpf       // v_rcp_f32
#define PKRTZ __builtin_amdgcn_cvt_pkrtz // v_cvt_pkrtz_f16_f32
#define MED3 __builtin_amdgcn_fmed3f     // v_med3_f32
#define FMA2 __builtin_elementwise_fma   // <2 x float> fma -> v_pk_fma_f32

#define L1C 1.4426950408889634f          // log2(e)
#define L2C 2.8853900817779268f          // 2*log2(e)

union H8 { unsigned int u[4]; half8v h; half2v h2[4]; };
union HU { fp16x2 h; unsigned int u; };

__device__ __forceinline__ unsigned int pk(float a, float b) {
    HU t; t.h = PKRTZ(a, b); return t.u;
}

// R19 = R17 exactly (the measured optimum: 279.0us) + decode loop unroll 2.
// R18's x-MFMA source-hoist regressed 2% (compiler already schedules what's
// legal; source-order games are noise) — reverted.
// R17 structure: one wave = private 16-batch group, private LDS h-region,
// no barriers, no lgkmcnt drain (DS in-order per wave), 2 waves/SIMD,
// float2-packed gate math (v_pk_*), encode unroll 2, evens-first h-MFMAs,
// anti-phase s_sleep stagger. Decode now also unroll 2 (same scheduling-
// window mechanism that bought +2% on encode).
// No arithmetic change anywhere: absmax must equal 9.766e-4 exactly.
// Concurrency map (measured, complete): (1/SIMD)=312-375, (2/SIMD)=279,
// (4/SIMD cell-split)=315; 8-batch/wave duplicates the whole instruction
// stream (issue is per-instruction, not per-useful-lane) — excluded on paper.
// C layout: row(batch)=quad*4+reg, col(gate)=lane&15; A: m=lane&15, k=quad*8+j.
__global__ __launch_bounds__(256, 2)
void lstm_mfma_kernel(const float* __restrict__ hist, const float* __restrict__ W_ih,
                      const float* __restrict__ W_hh, const float* __restrict__ b_ih,
                      const float* __restrict__ b_hh, const float* __restrict__ W_pred,
                      const float* __restrict__ b_pred, float* __restrict__ out)
{
    const int lane = threadIdx.x & 63;
    const int wv   = threadIdx.x >> 6;
    const int m    = lane & 15;
    const int quad = lane >> 4;
    const int elem0 = (blockIdx.x * 4 + wv) * 16;

    // anti-phase: co-resident pair assumed (k, k+256) for 512-block grid
    if ((blockIdx.x >> 8) & 1) __builtin_amdgcn_s_sleep(12);

    __shared__ __align__(16) float h_lds_all[4][16][LDS_PAD];
    float (*hl)[LDS_PAD] = h_lds_all[wv];    // per-wave region: no __syncthreads ever

    // ---- resident weight fragments (f16, exp-scale folded; tiles 0,1=i 2,3=f 4,5=g 6,7=o) ----
    const float esc[4] = { -L1C, -L1C, L2C, -L1C };   // i,f,g,o exp2-domain scales
    half8v Bh[8], B2[8];
    #pragma unroll
    for (int n = 0; n < 8; ++n) {
        const int gc = n * 16 + m;           // gate row 0..127
        const float sc = esc[n >> 1];
        H8 bh;
        #pragma unroll
        for (int jj = 0; jj < 4; ++jj) {
            bh.h2[jj] = (half2v){ (_Float16)(sc * W_hh[gc * HID + quad * 8 + 2 * jj]),
                                  (_Float16)(sc * W_hh[gc * HID + quad * 8 + 2 * jj + 1]) };
        }
        Bh[n] = bh.h;
        H8 b2; b2.u[0] = b2.u[1] = b2.u[2] = b2.u[3] = 0u;
        if (quad == 0) {
            b2.h2[0] = (half2v){ (_Float16)(sc * W_ih[gc * 4 + 0]), (_Float16)(sc * W_ih[gc * 4 + 1]) };
            b2.h2[1] = (half2v){ (_Float16)(sc * W_ih[gc * 4 + 2]), (_Float16)(sc * W_ih[gc * 4 + 3]) };
            float bsum = sc * (b_ih[gc] + b_hh[gc]);
            _Float16 bhi = (_Float16)bsum;
            _Float16 blo = (_Float16)(bsum - (float)bhi);   // bias exact to ~2^-24
            b2.h2[2] = (half2v){ bhi, blo };                // K rows 4,5 (A = 1,1)
        }
        B2[n] = b2.h;
    }
    const unsigned int one2 = 0x3C003C00u;   // (1.0h, 1.0h)
    const floatx4 zf4 = { 0.f, 0.f, 0.f, 0.f };

    // ---- init h = 0 (LDS), c = 0 (regs) ----
    float cst[2][4];
    #pragma unroll
    for (int hf = 0; hf < 2; ++hf)
        #pragma unroll
        for (int r = 0; r < 4; ++r) { cst[hf][r] = 0.f; hl[quad * 4 + r][hf * 16 + m] = 0.f; }
    // no drain needed: DS pipe is in-order per wave

    // ---- encode: 200 steps, unrolled 2x for scheduling window ----
    const float4* xp = (const float4*)(hist + (size_t)(elem0 + m) * (SEQLEN * 4));
    float4 xv = xp[0];
    #pragma unroll 2
    for (int t = 0; t < SEQLEN; ++t) {
        float4 h0 = *(const float4*)&hl[m][quad * 8];
        float4 h1 = *(const float4*)&hl[m][quad * 8 + 4];
        H8 ahu;
        ahu.u[0] = pk(h0.x, h0.y); ahu.u[1] = pk(h0.z, h0.w);
        ahu.u[2] = pk(h1.x, h1.y); ahu.u[3] = pk(h1.z, h1.w);
        const half8v ah = ahu.h;

        const unsigned int tx0 = pk(xv.x, xv.y), tx1 = pk(xv.z, xv.w);
        H8 a2u;
        a2u.u[0] = (quad == 0) ? tx0 : 0u;
        a2u.u[1] = (quad == 0) ? tx1 : 0u;
        a2u.u[2] = (quad == 0) ? one2 : 0u;
        a2u.u[3] = 0u;
        const half8v a2 = a2u.h;

        const int tn = (t + 1 < SEQLEN) ? t + 1 : SEQLEN - 1;
        float4 xn = xp[tn];                  // prefetch stays in flight

        // evens first: hf=0's acc tiles (0,2,4,6) complete earliest
        floatx4 acc[8];
        #pragma unroll
        for (int nn = 0; nn < 8; ++nn) {
            const int n = (nn < 4) ? (nn * 2) : ((nn - 4) * 2 + 1);
            floatx4 a = __builtin_amdgcn_mfma_f32_16x16x32_f16(a2, B2[n], zf4, 0, 0, 0);
            acc[n] = __builtin_amdgcn_mfma_f32_16x16x32_f16(ah, Bh[n], a, 0, 0, 0);
        }
        // gates arrive in exp2 domain; cell pairs packed as float2 -> v_pk_* ops
        #pragma unroll
        for (int hf = 0; hf < 2; ++hf) {
            #pragma unroll
            for (int pr = 0; pr < 2; ++pr) {
                const int r0 = pr * 2, r1 = r0 + 1;
                const float2v ei = { EXP2(acc[0 + hf][r0]), EXP2(acc[0 + hf][r1]) };
                const float2v ef = { EXP2(acc[2 + hf][r0]), EXP2(acc[2 + hf][r1]) };
                const float2v eg = { EXP2(acc[4 + hf][r0]), EXP2(acc[4 + hf][r1]) };
                const float2v eo = { EXP2(acc[6 + hf][r0]), EXP2(acc[6 + hf][r1]) };
                // cn = c/(1+ef) + (eg-1)/((1+ei)(1+eg)) ; rcp shared across pair
                const float2v pf = 1.f + ef;
                const float2v t1 = (1.f + ei) * (1.f + eg);
                const float2v cc = { cst[hf][r0], cst[hf][r1] };
                const float2v num = FMA2(cc, t1, (eg - 1.f) * pf);
                const float2v d  = t1 * pf;                 // <= 2^52 each
                const float   R  = RCPF(d.x * d.y);         // <= 2^104: safe
                const float2v dsw = { d.y, d.x };
                const float2v cn  = num * (R * dsw);
                // tanh input clamp +-12: EXACT (tanh(12)==1.0f in fp32)
                const float2v cna = { MED3(cn.x, -12.f, 12.f), MED3(cn.y, -12.f, 12.f) };
                const float2v ea  = cna * L2C;
                const float2v ec  = { EXP2(ea.x), EXP2(ea.y) };
                const float2v dh  = (1.f + eo) * (1.f + ec);
                const float   Rh  = RCPF(dh.x * dh.y);
                const float2v dhsw = { dh.y, dh.x };
                const float2v hn  = (ec - 1.f) * (Rh * dhsw);

                cst[hf][r0] = cn.x; cst[hf][r1] = cn.y;     // state UNclamped (matches ref)
                hl[quad * 4 + r0][hf * 16 + m] = hn.x;
                hl[quad * 4 + r1][hf * 16 + m] = hn.y;
            }
        }
        // no lgkmcnt drain: DS in-order per wave; compiler can't hoist the
        // may-aliasing next-step reads above these writes
        xv = xn;
    }

    // ---- decode: 50 steps (c reset to 0 -> f-gate dead; tiles 2,3 skipped) ----
    float wp[4][8];
    #pragma unroll
    for (int d = 0; d < 4; ++d)
        #pragma unroll
        for (int j = 0; j < 8; ++j) wp[d][j] = W_pred[d * HID + quad * 8 + j];
    float bp[4] = { b_pred[0], b_pred[1], b_pred[2], b_pred[3] };

    float* op = out + (size_t)(elem0 + m) * (PSTEPS * 4);
    #pragma unroll 2
    for (int p = 0; p < PSTEPS; ++p) {
        float4 h0 = *(const float4*)&hl[m][quad * 8];
        float4 h1 = *(const float4*)&hl[m][quad * 8 + 4];
        const float hv[8] = { h0.x, h0.y, h0.z, h0.w, h1.x, h1.y, h1.z, h1.w };

        float pd[4];
        #pragma unroll
        for (int d = 0; d < 4; ++d) {
            float s = 0.f;
            #pragma unroll
            for (int j = 0; j < 8; ++j) s = fmaf(hv[j], wp[d][j], s);
            s += __shfl_xor(s, 16);
            s += __shfl_xor(s, 32);
            pd[d] = s + bp[d];
        }
        if (quad == 0) *(float4*)(op + p * 4) = make_float4(pd[0], pd[1], pd[2], pd[3]);

        if (p + 1 < PSTEPS) {
            H8 ahu;
            ahu.u[0] = pk(hv[0], hv[1]); ahu.u[1] = pk(hv[2], hv[3]);
            ahu.u[2] = pk(hv[4], hv[5]); ahu.u[3] = pk(hv[6], hv[7]);
            const half8v ah = ahu.h;
            const unsigned int tx0 = pk(pd[0], pd[1]), tx1 = pk(pd[2], pd[3]);
            H8 a2u;
            a2u.u[0] = (quad == 0) ? tx0 : 0u;
            a2u.u[1] = (quad == 0) ? tx1 : 0u;
            a2u.u[2] = (quad == 0) ? one2 : 0u;
            a2u.u[3] = 0u;
            const half8v a2 = a2u.h;

            floatx4 acc[6];   // tiles 0,1=i ; 4,5=g ; 6,7=o
            #pragma unroll
            for (int nn = 0; nn < 6; ++nn) {
                const int n = (nn < 2) ? nn : nn + 2;
                floatx4 a = __builtin_amdgcn_mfma_f32_16x16x32_f16(a2, B2[n], zf4, 0, 0, 0);
                acc[nn] = __builtin_amdgcn_mfma_f32_16x16x32_f16(ah, Bh[n], a, 0, 0, 0);
            }
            #pragma unroll
            for (int hf = 0; hf < 2; ++hf) {
                #pragma unroll
                for (int pr = 0; pr < 2; ++pr) {
                    const int r0 = pr * 2, r1 = r0 + 1;
                    const float2v ei = { EXP2(acc[0 + hf][r0]), EXP2(acc[0 + hf][r1]) };
                    const float2v eg = { EXP2(acc[2 + hf][r0]), EXP2(acc[2 + hf][r1]) };
                    const float2v eo = { EXP2(acc[4 + hf][r0]), EXP2(acc[4 + hf][r1]) };
                    // cn = (eg-1)/((1+ei)(1+eg)) (c==0); |cn|<1
                    const float2v d  = (1.f + ei) * (1.f + eg);
                    const float   R  = RCPF(d.x * d.y);
                    const float2v dsw = { d.y, d.x };
                    const float2v cn  = (eg - 1.f) * (R * dsw);
                    const float2v ea  = cn * L2C;
                    const float2v ec  = { EXP2(ea.x), EXP2(ea.y) };   // ec in [2^-2.9, 2^2.9]
                    const float2v dh  = (1.f + eo) * (1.f + ec);
                    const float   Rh  = RCPF(dh.x * dh.y);
                    const float2v dhsw = { dh.y, dh.x };
                    const float2v hn  = (ec - 1.f) * (Rh * dhsw);

                    hl[quad * 4 + r0][hf * 16 + m] = hn.x;
                    hl[quad * 4 + r1][hf * 16 + m] = hn.y;
                }
            }
            // no lgkmcnt drain (DS in-order per wave)
        }
    }
}

extern "C" void kernel_launch(void* const* d_in, const int* in_sizes, int n_in,
                              void* d_out, int out_size, void* d_ws, size_t ws_size,
                              hipStream_t stream) {
    const float* hist   = (const float*)d_in[0];
    const float* W_ih   = (const float*)d_in[1];
    const float* W_hh   = (const float*)d_in[2];
    const float* b_ih   = (const float*)d_in[3];
    const float* b_hh   = (const float*)d_in[4];
    const float* W_pred = (const float*)d_in[5];
    const float* b_pred = (const float*)d_in[6];
    float* out = (float*)d_out;

    const int blocks = (BATCH / 16) / 4;   // 512 blocks = 2048 waves, 2/SIMD
    lstm_mfma_kernel<<<blocks, 256, 0, stream>>>(hist, W_ih, W_hh, b_ih, b_hh,
                                                 W_pred, b_pred, out);
}